// Round 4
// baseline (508.135 us; speedup 1.0000x reference)
//
#include <hip/hip_runtime.h>

// Circuit scan, two-phase:
//   A) X = sigmoid(4*clip(P,-2,2)), transposed [r][(b,t)] -> Xt[(b,t)][r]
//      (pure streaming transpose; fixes the 1-MiB-strided reads that made
//       rounds 1/3 HBM-random-access-bound at ~380 us)
//   B) per-batch scan: states[r] <- a+b-2ab, operands gathered from
//      concat(x_t, states); 1 block = 1 wave = 1 batch, zero barriers
//      (same-wave DS ops execute in program order).
#define N_IN   256
#define N_REG  256
#define NBATCH 4096
#define TT     64
#define PLANE  ((size_t)NBATCH * TT)   // 262144 floats per P row
#define TC     8                        // timesteps staged per chunk in B
#define NCHUNK (TT / TC)
#define ST_BASE (TC * N_IN)             // state region base (words) in B's LDS

// ---------------- Kernel A: sigmoid + transpose ----------------
// in : P[256][262144]  (row stride 1 MiB)
// out: Xt[262144][256] (each (b,t) row = 1 KB contiguous)
__global__ __launch_bounds__(256) void sig_transpose(
    const float* __restrict__ P, float* __restrict__ Xt)
{
    __shared__ float tile[64][65];       // LD=65: 2-way (free) banks both phases
    const int tid  = threadIdx.x;
    const int rt   = blockIdx.x & 3;     // 4 r-tiles
    const size_t ct = blockIdx.x >> 2;   // 4096 bt-tiles
    const int r0   = rt * 64;
    const size_t c0 = ct * 64;
    const int col4 = (tid & 15) * 4;     // 0..60
    const int row  = tid >> 4;           // 0..15

    #pragma unroll
    for (int i = 0; i < 4; ++i) {
        const int ri = row + 16 * i;     // r-local
        const float4 v = *reinterpret_cast<const float4*>(
            P + (size_t)(r0 + ri) * PLANE + c0 + col4);
        const float xs[4] = {v.x, v.y, v.z, v.w};
        #pragma unroll
        for (int j = 0; j < 4; ++j) {
            float x = fminf(2.0f, fmaxf(-2.0f, xs[j]));
            tile[ri][col4 + j] = 1.0f / (1.0f + __expf(-4.0f * x));
        }
    }
    __syncthreads();
    #pragma unroll
    for (int i = 0; i < 4; ++i) {
        const int ci = row + 16 * i;     // bt-local
        float4 w;
        w.x = tile[col4 + 0][ci];
        w.y = tile[col4 + 1][ci];
        w.z = tile[col4 + 2][ci];
        w.w = tile[col4 + 3][ci];
        *reinterpret_cast<float4*>(Xt + (c0 + ci) * 256 + r0 + col4) = w;
    }
}

// ---------------- Kernel B: wave-per-batch scan ----------------
__global__ __launch_bounds__(64, 4) void circuit_scan(
    const float* __restrict__ Xt,
    const int*   __restrict__ wa,
    const int*   __restrict__ wb,
    float*       __restrict__ out)
{
    // lds[0 .. 2048)        xt[t][r] for current chunk (t local, LD=256)
    // lds[2048 .. 2304)     states
    __shared__ float lds[ST_BASE + N_REG];   // 9216 B -> ~16 blocks/CU

    const int lane = threadIdx.x;            // 0..63
    const int b    = blockIdx.x;
    const float* Xb = Xt + (size_t)b * (TT * N_IN);   // 64 KB contiguous

    const float* pa0[4]; const float* pb0[4];
    int inca[4], incb[4];
    float sv[4];

    #pragma unroll
    for (int k = 0; k < 4; ++k) {
        const int r  = lane + 64 * k;
        const int ia = wa[r];
        const int ib = wb[r];
        const bool ax = ia < N_IN;
        const bool bx = ib < N_IN;
        pa0[k] = lds + (ax ? ia : ST_BASE + (ia - N_IN));
        pb0[k] = lds + (bx ? ib : ST_BASE + (ib - N_IN));
        inca[k] = ax ? N_IN : 0;             // x-operand walks +256 words per t
        incb[k] = bx ? N_IN : 0;
        lds[ST_BASE + r] = 0.5f;
        sv[k] = 0.5f;
    }

    // Prefetch chunk 0: lane loads float4 of each of TC t-rows (1 KB/row, coalesced)
    float4 pf[TC];
    #pragma unroll
    for (int t = 0; t < TC; ++t)
        pf[t] = *reinterpret_cast<const float4*>(Xb + (size_t)t * N_IN + lane * 4);

    for (int c = 0; c < NCHUNK; ++c) {
        // stage chunk into LDS (b128, conflict-free contiguous writes)
        #pragma unroll
        for (int t = 0; t < TC; ++t)
            *reinterpret_cast<float4*>(&lds[t * N_IN + lane * 4]) = pf[t];
        // issue next chunk's loads; complete under the scan
        if (c + 1 < NCHUNK) {
            #pragma unroll
            for (int t = 0; t < TC; ++t)
                pf[t] = *reinterpret_cast<const float4*>(
                    Xb + (size_t)((c + 1) * TC + t) * N_IN + lane * 4);
        }
        // scan TC steps: 8 gathers + 4 updates + 4 state writes, no barriers
        const float* pa[4]; const float* pb[4];
        #pragma unroll
        for (int k = 0; k < 4; ++k) { pa[k] = pa0[k]; pb[k] = pb0[k]; }

        #pragma unroll
        for (int t = 0; t < TC; ++t) {
            float av[4], bv[4];
            #pragma unroll
            for (int k = 0; k < 4; ++k) { av[k] = *pa[k]; bv[k] = *pb[k]; }
            #pragma unroll
            for (int k = 0; k < 4; ++k) {
                const float a  = av[k];
                const float bb = bv[k];
                const float ns = a + bb - 2.0f * a * bb;
                sv[k] = ns;
                lds[ST_BASE + lane + 64 * k] = ns;
                pa[k] += inca[k];
                pb[k] += incb[k];
            }
        }
    }

    #pragma unroll
    for (int k = 0; k < 4; ++k)
        out[(size_t)b * N_REG + lane + 64 * k] = sv[k];
}

extern "C" void kernel_launch(void* const* d_in, const int* in_sizes, int n_in,
                              void* d_out, int out_size, void* d_ws, size_t ws_size,
                              hipStream_t stream) {
    const float* P   = (const float*)d_in[0];
    const int*   wa  = (const int*)d_in[1];
    const int*   wb  = (const int*)d_in[2];
    float*       out = (float*)d_out;
    float*       Xt  = (float*)d_ws;       // 256 MB scratch

    sig_transpose<<<16384, 256, 0, stream>>>(P, Xt);
    circuit_scan<<<NBATCH, 64, 0, stream>>>(Xt, wa, wb, out);
}